// Round 4
// baseline (4653.996 us; speedup 1.0000x reference)
//
#include <hip/hip_runtime.h>
#include <stdint.h>

// ---------------------------------------------------------------------------
// 2-layer LSTM (T=256, B=256, F=128, H=1024) for MI355X (gfx950).
// R10: skeleton attack. R9 showed waves-in-lockstep saturate within-phase
// hiding (MfmaUtil 14% == MFMA-cyc/step-cyc exactly); the cost is the serial
// per-step skeleton. Changes:
//   (1) Stamp-based producer/consumer sync: each WG posts stamp[mi][ni]=gen
//       after its h-store drain. Consumer wave wv polls only its 2 producer
//       chunks (ni=2wv,2wv+1), buffer_inv, reg-copies 2x2KB into As. Staging
//       overlaps the straggler window; no counting barrier, no global detect.
//   (2) Syncs/step 5 -> 3 (post-MFMA sync removed: gbuf slots are per-wave
//       exclusive; As-overwrite fenced by the (3)/(4)/(1) chain).
//   (3) Busy-poll 64 iters before s_sleep.
//   (4) AS_STRIDE back to 2080 (R7 measured-good; 2096 doubled conflicts).
// Heavy fallback (probe fails co-XCD): wave0 polls all 32 stamps + agent
// acquire, then stage. Probe rewritten on stamps, same salt/poison tokens.
// ---------------------------------------------------------------------------

typedef __bf16 bf16x8 __attribute__((ext_vector_type(8)));
typedef float  f32x4  __attribute__((ext_vector_type(4)));
typedef unsigned short ushort8v __attribute__((ext_vector_type(8)));
typedef unsigned short ushort4v __attribute__((ext_vector_type(4)));
typedef unsigned int   uint4v   __attribute__((ext_vector_type(4)));
typedef __attribute__((address_space(1))) unsigned int as1_u32;
typedef __attribute__((address_space(3))) unsigned int as3_u32;

#define T_STEPS 256
#define BATCH   256
#define HDIM    1024
#define GDIM    4096
#define FDIM    128
#define AS_STRIDE 2080   // bytes/row in LDS h slab (R7 measured-good)

static __device__ __forceinline__ float bf2f(unsigned short u) {
  union { unsigned int i; float f; } v; v.i = ((unsigned int)u) << 16; return v.f;
}
static __device__ __forceinline__ unsigned short f2bf(float f) {
  return __builtin_bit_cast(unsigned short, (__bf16)f);
}
static __device__ __forceinline__ float sigm(float x) { return 1.f / (1.f + __expf(-x)); }
static __device__ __forceinline__ float tanh_f(float x) { return 2.f / (1.f + __expf(-2.f * x)) - 1.f; }

// Invalidate this CU's vector L1 (32KB). Much cheaper than agent acquire.
static __device__ __forceinline__ void vl1_inv() {
  asm volatile("buffer_inv" ::: "memory");
}

__global__ void conv_bf16(const float* __restrict__ s, unsigned short* __restrict__ d, int n) {
  int i = blockIdx.x * 256 + threadIdx.x;
  if (i < n) d[i] = f2bf(s[i]);
}

__global__ void diag_kernel(float* out, int n, float v) {
  int i = blockIdx.x * 256 + threadIdx.x;
  if (i < n) out[i] = v;
}

// ------------------------- stamp-based group sync ---------------------------
// stamps = bar + mi*32: one u32 per producer WG (ni). Monotonic generations.
// Producer: after a __syncthreads() that drained its h-stores (vmcnt 0 -> L2),
// lane0 posts stamp=gen (relaxed agent atomic; release fence first if heavy).
// Consumer: poll (int)(g - target) >= 0 (poison 0xAAAAAAAA reads negative).
__device__ __forceinline__ void post_stamp(unsigned int* st, unsigned int gen, bool fast) {
  if (!fast) __builtin_amdgcn_fence(__ATOMIC_RELEASE, "agent");
  __hip_atomic_store(st, gen, __ATOMIC_RELAXED, __HIP_MEMORY_SCOPE_AGENT);
}
__device__ __forceinline__ void poll_ge(unsigned int* st, unsigned int target) {
  for (unsigned int it = 0; it < (1u << 15); ++it) {
    unsigned int g = __hip_atomic_load(st, __ATOMIC_RELAXED, __HIP_MEMORY_SCOPE_AGENT);
    if ((int)(g - target) >= 0) return;
    if (it > 64) __builtin_amdgcn_s_sleep(1);
  }
}

// Copy one producer chunk (32 rows x 32 h-cols, 2KB) from global h into As.
// lane l: row = l>>2 (+16 for second half), colpart = l&3 (8 bf16 = 16B).
__device__ __forceinline__ void copy_chunk(const unsigned short* __restrict__ src,
                                           char* AsB, int r0, int ni2, int lane) {
  int rlo = lane >> 2, cp = lane & 3;
  const unsigned short* s0 = src + (size_t)(r0 + rlo) * HDIM + ni2 * 32 + cp * 8;
  uint4v a = *(const uint4v*)(s0);
  uint4v b = *(const uint4v*)(s0 + 16 * HDIM);
  char* d0 = AsB + rlo * AS_STRIDE + ni2 * 64 + cp * 16;
  *(uint4v*)(d0) = a;
  *(uint4v*)(d0 + 16 * AS_STRIDE) = b;
}

// --------------------------- gemm_bt: C = A @ B^T ---------------------------
__global__ __launch_bounds__(256) void gemm_bt_xw(
    const unsigned short* __restrict__ A,
    const unsigned short* __restrict__ B,
    unsigned short* __restrict__ xw,
    int K)
{
  const int tid = threadIdx.x, lane = tid & 63, w = tid >> 6;
  const int m0 = blockIdx.x * 128;
  const int n0 = blockIdx.y * 128;
  __shared__ unsigned short As[128 * 64];
  __shared__ unsigned short Bs[128 * 64];
  const int mrow0 = (w & 1) * 64, ncol0 = (w >> 1) * 64;
  const int quad = lane >> 4;

  f32x4 acc[4][4];
  #pragma unroll
  for (int i = 0; i < 4; ++i)
    #pragma unroll
    for (int j = 0; j < 4; ++j) acc[i][j] = f32x4{0.f, 0.f, 0.f, 0.f};

  const int kiter = K >> 6;
  for (int ki = 0; ki < kiter; ++ki) {
    const int k0 = ki * 64;
    __syncthreads();
    #pragma unroll
    for (int i = 0; i < 4; ++i) {
      int obase = (w * 4 + i) * 1024;          // wave-uniform LDS byte base
      int o = obase + lane * 16;
      int row = o >> 7; int kb = o & 127;
      const char* ga = (const char*)A + ((size_t)(m0 + row) * K + k0) * 2 + kb;
      const char* gb = (const char*)B + ((size_t)(n0 + row) * K + k0) * 2 + kb;
      __builtin_amdgcn_global_load_lds((const as1_u32*)ga, (as3_u32*)((char*)As + obase), 16, 0, 0);
      __builtin_amdgcn_global_load_lds((const as1_u32*)gb, (as3_u32*)((char*)Bs + obase), 16, 0, 0);
    }
    __syncthreads();
    #pragma unroll
    for (int kk = 0; kk < 2; ++kk) {
      bf16x8 af[4], bfr[4];
      #pragma unroll
      for (int mt = 0; mt < 4; ++mt)
        af[mt] = *(const bf16x8*)(As + (mrow0 + mt * 16 + (lane & 15)) * 64 + kk * 32 + quad * 8);
      #pragma unroll
      for (int nt = 0; nt < 4; ++nt)
        bfr[nt] = *(const bf16x8*)(Bs + (ncol0 + nt * 16 + (lane & 15)) * 64 + kk * 32 + quad * 8);
      #pragma unroll
      for (int mt = 0; mt < 4; ++mt)
        #pragma unroll
        for (int nt = 0; nt < 4; ++nt)
          acc[mt][nt] = __builtin_amdgcn_mfma_f32_16x16x32_bf16(af[mt], bfr[nt], acc[mt][nt], 0, 0, 0);
    }
  }
  #pragma unroll
  for (int mt = 0; mt < 4; ++mt) {
    int m = m0 + mrow0 + mt * 16 + quad * 4;
    int tl = m >> 8, b = m & 255;
    #pragma unroll
    for (int nt = 0; nt < 4; ++nt) {
      int col = n0 + ncol0 + nt * 16 + (lane & 15);
      ushort4v v;
      v.x = f2bf(acc[mt][nt][0]); v.y = f2bf(acc[mt][nt][1]);
      v.z = f2bf(acc[mt][nt][2]); v.w = f2bf(acc[mt][nt][3]);
      *(ushort4v*)(xw + ((size_t)tl * GDIM + col) * BATCH + b) = v;
    }
  }
}

// ---------------- probe: validate intra-XCD visibility for this group --------
// token plain-store -> drain -> stamp post -> tid0 polls all 32 stamps ->
// vL1 inv -> plain reads of all 32 tokens. d_ws is re-poisoned 0xAA before
// every launch; prior-kernel salts were flushed to LLC at kernel end, so a
// cross-XCD member always mismatches -> heavy fences all launch.
__device__ __forceinline__ bool probe_chk(unsigned int* probeBuf, unsigned int* stamps,
                                          unsigned int salt, unsigned int target,
                                          unsigned int* flagLds) {
  const int wg = blockIdx.x, mi = wg & 7, ni = wg >> 3;
  const int tid = threadIdx.x;
  if (tid == 0) probeBuf[wg * 32] = salt ^ (unsigned int)wg;
  __syncthreads();   // drains token store to L2
  if (tid == 0) {
    __hip_atomic_store(&stamps[ni], target, __ATOMIC_RELAXED, __HIP_MEMORY_SCOPE_AGENT);
    for (int k = 0; k < 32; ++k) poll_ge(&stamps[k], target);
    vl1_inv();
    unsigned int bad = 0;
    for (int k = 0; k < 32; ++k) {
      int member = mi + 8 * k;
      unsigned int v = probeBuf[member * 32];
      if (v != (salt ^ (unsigned int)member)) bad = 1;
    }
    *flagLds = bad;
  }
  __syncthreads();
  return (*flagLds == 0);
}

// --------------------------- layer 0: fused persistent chunk -----------------
// 256 WGs x 1024 thr, 1/CU. WG (mi=wg&7, ni=wg>>3): rows [32mi,+32), cols [32ni,+32).
// Wave wv: gate g=wv&3, K-quarter kq=wv>>2. whh[2][8]=64 VGPR/wave.
__global__ __launch_bounds__(1024, 4) void lstm_layer0_kernel(
    const unsigned short* __restrict__ xbf,  // (T,B,F) bf16
    const float* __restrict__ Wih,           // (4096,128) fp32
    const float* __restrict__ Whh,           // (4096,1024) fp32
    const float* __restrict__ bih,
    const float* __restrict__ bhh,
    unsigned short* __restrict__ slab,       // (ch_len+1, B, H) bf16, gemm feed
    unsigned short* __restrict__ hx,         // 2-slot ping-pong exchange (hot)
    float* __restrict__ cstate,              // (B,H) fp32
    int t0, int ch_len, unsigned int gen_base,
    float* __restrict__ dout_h,
    float* __restrict__ dout_c,
    unsigned int* __restrict__ bar,
    unsigned int* __restrict__ probe)
{
  const int tid = threadIdx.x, lane = tid & 63, wv = tid >> 6;   // wv 0..15
  const int quad = lane >> 4, l15 = lane & 15;
  const int g = wv & 3, kq = wv >> 2;
  const int wg = blockIdx.x;
  const int mi = wg & 7, ni = wg >> 3;
  const int r0 = mi * 32, hc0 = ni * 32;
  unsigned int* stamps = bar + mi * 32;   // 32 producer stamps for this group

  __shared__ unsigned short As[32 * (AS_STRIDE / 2)];
  __shared__ float gbuf[16][32][33];     // reads bank = hcl+row: <=2-way (free)
  __shared__ unsigned int flagLds;

  // W_hh fragment: gate g, K-quarter kq (32 cols x 256 k, bf16 in regs)
  bf16x8 whh[2][8];
  #pragma unroll
  for (int nt = 0; nt < 2; ++nt) {
    const float* wrow = Whh + (size_t)(g * HDIM + hc0 + nt * 16 + l15) * HDIM + kq * 256 + quad * 8;
    #pragma unroll
    for (int kk = 0; kk < 8; ++kk) {
      f32x4 f0 = *(const f32x4*)(wrow + kk * 32);
      f32x4 f1 = *(const f32x4*)(wrow + kk * 32 + 4);
      bf16x8 r;
      r[0] = (__bf16)f0[0]; r[1] = (__bf16)f0[1]; r[2] = (__bf16)f0[2]; r[3] = (__bf16)f0[3];
      r[4] = (__bf16)f1[0]; r[5] = (__bf16)f1[1]; r[6] = (__bf16)f1[2]; r[7] = (__bf16)f1[3];
      whh[nt][kk] = r;
    }
  }
  // W_ih fragment: K=128 split across 4 kq (32 each)
  bf16x8 wih[2];
  #pragma unroll
  for (int nt = 0; nt < 2; ++nt) {
    const float* wrow = Wih + (size_t)(g * HDIM + hc0 + nt * 16 + l15) * FDIM + kq * 32 + quad * 8;
    f32x4 f0 = *(const f32x4*)(wrow);
    f32x4 f1 = *(const f32x4*)(wrow + 4);
    bf16x8 r;
    r[0] = (__bf16)f0[0]; r[1] = (__bf16)f0[1]; r[2] = (__bf16)f0[2]; r[3] = (__bf16)f0[3];
    r[4] = (__bf16)f1[0]; r[5] = (__bf16)f1[1]; r[6] = (__bf16)f1[2]; r[7] = (__bf16)f1[3];
    wih[nt] = r;
  }

  const int hcl = tid & 31, row = tid >> 5;   // EW: 1 (row, hcol) elem/thread
  float bias[4];
  #pragma unroll
  for (int b4 = 0; b4 < 4; ++b4)
    bias[b4] = bih[b4 * HDIM + hc0 + hcl] + bhh[b4 * HDIM + hc0 + hcl];

  float c1 = (t0 == 0) ? 0.f : cstate[(size_t)(r0 + row) * HDIM + hc0 + hcl];

  unsigned int salt = 0x9E3779B9u ^ (gen_base * 2654435761u);
  bool fast = probe_chk(probe, stamps, salt, gen_base + 1u, &flagLds);

  const int tend = t0 + ch_len;

  // prologue: cross-kernel h stage (prev launch's stores are stream-visible)
  if (t0 > 0) {
    const unsigned short* hsrc = hx + (size_t)((t0 - 1) & 1) * (BATCH * HDIM);
    copy_chunk(hsrc, (char*)As, r0, wv * 2, lane);
    copy_chunk(hsrc, (char*)As, r0, wv * 2 + 1, lane);
  }
  // prologue: x-projection for the first step of this chunk (K-quarter slice)
  f32x4 acc[2][2];
  #pragma unroll
  for (int mt = 0; mt < 2; ++mt)
    #pragma unroll
    for (int nt = 0; nt < 2; ++nt) acc[mt][nt] = f32x4{0.f, 0.f, 0.f, 0.f};
  {
    bf16x8 af[2];
    #pragma unroll
    for (int mt = 0; mt < 2; ++mt)
      af[mt] = *(const bf16x8*)(xbf + (size_t)(t0 * BATCH + r0 + mt * 16 + l15) * FDIM + kq * 32 + quad * 8);
    #pragma unroll
    for (int mt = 0; mt < 2; ++mt)
      #pragma unroll
      for (int nt = 0; nt < 2; ++nt)
        acc[mt][nt] = __builtin_amdgcn_mfma_f32_16x16x32_bf16(af[mt], wih[nt], acc[mt][nt], 0, 0, 0);
  }
  __syncthreads();   // prologue stage visible before first MFMA

  #pragma unroll 1
  for (int t = t0; t < tend; ++t) {
    if (t > 0) {
      #pragma unroll
      for (int j = 0; j < 8; ++j) {
        bf16x8 af[2];
        #pragma unroll
        for (int mt = 0; mt < 2; ++mt)
          af[mt] = *(const bf16x8*)((const char*)As + (mt * 16 + l15) * AS_STRIDE + kq * 512 + j * 64 + quad * 16);
        #pragma unroll
        for (int mt = 0; mt < 2; ++mt)
          #pragma unroll
          for (int nt = 0; nt < 2; ++nt)
            acc[mt][nt] = __builtin_amdgcn_mfma_f32_16x16x32_bf16(af[mt], whh[nt][j], acc[mt][nt], 0, 0, 0);
      }
    }

    // gbuf write — no leading sync needed (per-wave-exclusive slot; readers
    // gated by the barrier below; As reads all complete before any wave
    // passes that barrier).
    #pragma unroll
    for (int mt = 0; mt < 2; ++mt)
      #pragma unroll
      for (int nt = 0; nt < 2; ++nt) {
        int hl = nt * 16 + l15;
        int rq = mt * 16 + quad * 4;
        #pragma unroll
        for (int i = 0; i < 4; ++i)
          gbuf[wv][hl][rq + i] = acc[mt][nt][i];
      }
    __syncthreads();   // (3) gbuf visible

    unsigned short* hdst = slab + (size_t)(t - t0 + 1) * (BATCH * HDIM);
    unsigned short* hxd  = hx + (size_t)(t & 1) * (BATCH * HDIM);
    {
      float gi = gbuf[0][hcl][row] + gbuf[4][hcl][row] + gbuf[8][hcl][row]  + gbuf[12][hcl][row] + bias[0];
      float gf = gbuf[1][hcl][row] + gbuf[5][hcl][row] + gbuf[9][hcl][row]  + gbuf[13][hcl][row] + bias[1];
      float gg = gbuf[2][hcl][row] + gbuf[6][hcl][row] + gbuf[10][hcl][row] + gbuf[14][hcl][row] + bias[2];
      float go = gbuf[3][hcl][row] + gbuf[7][hcl][row] + gbuf[11][hcl][row] + gbuf[15][hcl][row] + bias[3];
      float iv = sigm(gi), fv = sigm(gf), gv = tanh_f(gg), ov = sigm(go);
      float cn = fv * c1 + iv * gv;
      c1 = cn;
      float hv = ov * tanh_f(cn);
      int gidx = (r0 + row) * HDIM + hc0 + hcl;
      unsigned short hb = f2bf(hv);
      hxd[gidx] = hb;        // hot exchange
      hdst[gidx] = hb;       // gemm feed
      if (t == tend - 1) cstate[gidx] = cn;
      if (t == T_STEPS - 1) { dout_h[gidx] = hv; dout_c[gidx] = cn; }
    }
    __syncthreads();   // (4) drains h stores (vmcnt 0) -> visible at L2

    if (t != tend - 1) {
      const unsigned int tgt = gen_base + 2u + (unsigned int)(t - t0);
      if (tid == 0) post_stamp(&stamps[ni], tgt, fast);

      // hoisted: x-projection for step t+1 (independent of h(t))
      #pragma unroll
      for (int mt = 0; mt < 2; ++mt)
        #pragma unroll
        for (int nt = 0; nt < 2; ++nt) acc[mt][nt] = f32x4{0.f, 0.f, 0.f, 0.f};
      {
        bf16x8 af[2];
        #pragma unroll
        for (int mt = 0; mt < 2; ++mt)
          af[mt] = *(const bf16x8*)(xbf + (size_t)((t + 1) * BATCH + r0 + mt * 16 + l15) * FDIM + kq * 32 + quad * 8);
        #pragma unroll
        for (int mt = 0; mt < 2; ++mt)
          #pragma unroll
          for (int nt = 0; nt < 2; ++nt)
            acc[mt][nt] = __builtin_amdgcn_mfma_f32_16x16x32_bf16(af[mt], wih[nt], acc[mt][nt], 0, 0, 0);
      }

      const unsigned short* hsrc = hx + (size_t)(t & 1) * (BATCH * HDIM);
      if (fast) {
        // eager: each wave waits only for its 2 producers, then copies 2x2KB
        #pragma unroll
        for (int cc = 0; cc < 2; ++cc) {
          int ni2 = wv * 2 + cc;
          poll_ge(&stamps[ni2], tgt);
          vl1_inv();
          copy_chunk(hsrc, (char*)As, r0, ni2, lane);
        }
      } else {
        if (tid == 0) {
          for (int j = 0; j < 32; ++j) poll_ge(&stamps[j], tgt);
          __builtin_amdgcn_fence(__ATOMIC_ACQUIRE, "agent");
        }
        __syncthreads();
        copy_chunk(hsrc, (char*)As, r0, wv * 2, lane);
        copy_chunk(hsrc, (char*)As, r0, wv * 2 + 1, lane);
      }
      __syncthreads();   // (1) all chunks staged
    }
  }
}

// --------------------------- layer 1: persistent chunk ----------------------
__global__ __launch_bounds__(1024, 4) void lstm_layer1_kernel(
    const unsigned short* __restrict__ xw,   // (ch_len, 4096, 256) bf16
    const float* __restrict__ Whh,
    const float* __restrict__ bih,
    const float* __restrict__ bhh,
    unsigned short* __restrict__ hpp,        // 2-slot ping-pong
    float* __restrict__ cstate,
    int t0, int ch_len, unsigned int gen_base,
    unsigned short* __restrict__ h1t0,
    float* __restrict__ dout_h,
    float* __restrict__ dout_c,
    unsigned int* __restrict__ bar,
    unsigned int* __restrict__ probe)
{
  const int tid = threadIdx.x, lane = tid & 63, wv = tid >> 6;
  const int quad = lane >> 4, l15 = lane & 15;
  const int g = wv & 3, kq = wv >> 2;
  const int wg = blockIdx.x;
  const int mi = wg & 7, ni = wg >> 3;
  const int r0 = mi * 32, hc0 = ni * 32;
  unsigned int* stamps = bar + mi * 32;

  __shared__ unsigned short As[32 * (AS_STRIDE / 2)];
  __shared__ float gbuf[16][32][33];
  __shared__ unsigned int flagLds;

  bf16x8 whh[2][8];
  #pragma unroll
  for (int nt = 0; nt < 2; ++nt) {
    const float* wrow = Whh + (size_t)(g * HDIM + hc0 + nt * 16 + l15) * HDIM + kq * 256 + quad * 8;
    #pragma unroll
    for (int kk = 0; kk < 8; ++kk) {
      f32x4 f0 = *(const f32x4*)(wrow + kk * 32);
      f32x4 f1 = *(const f32x4*)(wrow + kk * 32 + 4);
      bf16x8 r;
      r[0] = (__bf16)f0[0]; r[1] = (__bf16)f0[1]; r[2] = (__bf16)f0[2]; r[3] = (__bf16)f0[3];
      r[4] = (__bf16)f1[0]; r[5] = (__bf16)f1[1]; r[6] = (__bf16)f1[2]; r[7] = (__bf16)f1[3];
      whh[nt][kk] = r;
    }
  }

  const int hcl = tid & 31, row = tid >> 5;
  float bias[4];
  #pragma unroll
  for (int b4 = 0; b4 < 4; ++b4)
    bias[b4] = bih[b4 * HDIM + hc0 + hcl] + bhh[b4 * HDIM + hc0 + hcl];

  float c1 = (t0 == 0) ? 0.f : cstate[(size_t)(r0 + row) * HDIM + hc0 + hcl];

  unsigned int salt = 0xB5297A4Du ^ (gen_base * 2654435761u);
  bool fast = probe_chk(probe, stamps, salt, gen_base + 1u, &flagLds);

  const int tend = t0 + ch_len;

  // prologue: cross-kernel h stage + xw loads for first step
  if (t0 > 0) {
    const unsigned short* hsrc = hpp + (size_t)((t0 - 1) & 1) * (BATCH * HDIM);
    copy_chunk(hsrc, (char*)As, r0, wv * 2, lane);
    copy_chunk(hsrc, (char*)As, r0, wv * 2 + 1, lane);
  }
  float xwv[4];
  #pragma unroll
  for (int g4 = 0; g4 < 4; ++g4) {
    const unsigned short* xp =
        xw + ((size_t)0 * GDIM + g4 * HDIM + hc0 + hcl) * BATCH + r0 + row;
    xwv[g4] = bf2f(*xp);
  }
  __syncthreads();

  #pragma unroll 1
  for (int t = t0; t < tend; ++t) {
    f32x4 acc[2][2];
    #pragma unroll
    for (int mt = 0; mt < 2; ++mt)
      #pragma unroll
      for (int nt = 0; nt < 2; ++nt) acc[mt][nt] = f32x4{0.f, 0.f, 0.f, 0.f};

    if (t > 0) {
      #pragma unroll
      for (int j = 0; j < 8; ++j) {
        bf16x8 af[2];
        #pragma unroll
        for (int mt = 0; mt < 2; ++mt)
          af[mt] = *(const bf16x8*)((const char*)As + (mt * 16 + l15) * AS_STRIDE + kq * 512 + j * 64 + quad * 16);
        #pragma unroll
        for (int mt = 0; mt < 2; ++mt)
          #pragma unroll
          for (int nt = 0; nt < 2; ++nt)
            acc[mt][nt] = __builtin_amdgcn_mfma_f32_16x16x32_bf16(af[mt], whh[nt][j], acc[mt][nt], 0, 0, 0);
      }
    }

    #pragma unroll
    for (int mt = 0; mt < 2; ++mt)
      #pragma unroll
      for (int nt = 0; nt < 2; ++nt) {
        int hl = nt * 16 + l15;
        int rq = mt * 16 + quad * 4;
        #pragma unroll
        for (int i = 0; i < 4; ++i)
          gbuf[wv][hl][rq + i] = acc[mt][nt][i];
      }
    __syncthreads();   // (3)

    unsigned short* hdst = hpp + (size_t)(t & 1) * (BATCH * HDIM);
    {
      float gi = gbuf[0][hcl][row] + gbuf[4][hcl][row] + gbuf[8][hcl][row]  + gbuf[12][hcl][row] + xwv[0] + bias[0];
      float gf = gbuf[1][hcl][row] + gbuf[5][hcl][row] + gbuf[9][hcl][row]  + gbuf[13][hcl][row] + xwv[1] + bias[1];
      float gg = gbuf[2][hcl][row] + gbuf[6][hcl][row] + gbuf[10][hcl][row] + gbuf[14][hcl][row] + xwv[2] + bias[2];
      float go = gbuf[3][hcl][row] + gbuf[7][hcl][row] + gbuf[11][hcl][row] + gbuf[15][hcl][row] + xwv[3] + bias[3];
      float iv = sigm(gi), fv = sigm(gf), gv = tanh_f(gg), ov = sigm(go);
      float cn = fv * c1 + iv * gv;
      c1 = cn;
      float hv = ov * tanh_f(cn);
      int gidx = (r0 + row) * HDIM + hc0 + hcl;
      hdst[gidx] = f2bf(hv);
      if (h1t0 != nullptr && t == 0) h1t0[gidx] = f2bf(hv);
      if (t == tend - 1) cstate[gidx] = cn;
      if (t == T_STEPS - 1) { dout_h[gidx] = hv; dout_c[gidx] = cn; }
    }
    __syncthreads();   // (4)

    if (t != tend - 1) {
      const unsigned int tgt = gen_base + 2u + (unsigned int)(t - t0);
      if (tid == 0) post_stamp(&stamps[ni], tgt, fast);

      // hoisted: xw loads for step t+1
      #pragma unroll
      for (int g4 = 0; g4 < 4; ++g4) {
        const unsigned short* xp =
            xw + ((size_t)(t + 1 - t0) * GDIM + g4 * HDIM + hc0 + hcl) * BATCH + r0 + row;
        xwv[g4] = bf2f(*xp);
      }

      const unsigned short* hsrc = hpp + (size_t)(t & 1) * (BATCH * HDIM);
      if (fast) {
        #pragma unroll
        for (int cc = 0; cc < 2; ++cc) {
          int ni2 = wv * 2 + cc;
          poll_ge(&stamps[ni2], tgt);
          vl1_inv();
          copy_chunk(hsrc, (char*)As, r0, ni2, lane);
        }
      } else {
        if (tid == 0) {
          for (int j = 0; j < 32; ++j) poll_ge(&stamps[j], tgt);
          __builtin_amdgcn_fence(__ATOMIC_ACQUIRE, "agent");
        }
        __syncthreads();
        copy_chunk(hsrc, (char*)As, r0, wv * 2, lane);
        copy_chunk(hsrc, (char*)As, r0, wv * 2 + 1, lane);
      }
      __syncthreads();   // (1)
    }
  }
}

__global__ void y_kernel(const unsigned short* __restrict__ h1t0,
                         const unsigned short* __restrict__ wlin,
                         const float* __restrict__ blin,
                         float* __restrict__ y)
{
  int b = blockIdx.x;
  int f = threadIdx.x;
  const ushort8v* hp = (const ushort8v*)(h1t0 + (size_t)b * HDIM);
  const ushort8v* wp = (const ushort8v*)(wlin + (size_t)f * HDIM);
  float acc = 0.f;
  for (int i = 0; i < HDIM / 8; ++i) {
    ushort8v hv = hp[i], wvv = wp[i];
    #pragma unroll
    for (int j = 0; j < 8; ++j) acc += bf2f(hv[j]) * bf2f(wvv[j]);
  }
  y[b * FDIM + f] = acc + blin[f];
}

// ---------------------------------------------------------------------------
extern "C" void kernel_launch(void* const* d_in, const int* in_sizes, int n_in,
                              void* d_out, int out_size, void* d_ws, size_t ws_size,
                              hipStream_t stream) {
  (void)in_sizes; (void)n_in; (void)out_size;
  const float* x    = (const float*)d_in[0];
  const float* Wih0 = (const float*)d_in[1];
  const float* Whh0 = (const float*)d_in[2];
  const float* bih0 = (const float*)d_in[3];
  const float* bhh0 = (const float*)d_in[4];
  const float* Wih1 = (const float*)d_in[5];
  const float* Whh1 = (const float*)d_in[6];
  const float* bih1 = (const float*)d_in[7];
  const float* bhh1 = (const float*)d_in[8];
  const float* Wlin = (const float*)d_in[9];
  const float* blin = (const float*)d_in[10];
  float* out = (float*)d_out;

  const size_t SZ_BAR   = 4096;
  const size_t SZ_PROBE = 32768;
  const size_t SZ_XBF   = (size_t)T_STEPS * BATCH * FDIM * 2;
  const size_t SZ_WIH1  = (size_t)GDIM * HDIM * 2;
  const size_t SZ_WLIN  = (size_t)FDIM * HDIM * 2;
  const size_t SZ_HPP   = (size_t)2 * BATCH * HDIM * 2;
  const size_t SZ_HX    = (size_t)2 * BATCH * HDIM * 2;
  const size_t SZ_H1T0  = (size_t)BATCH * HDIM * 2;
  const size_t SZ_CST   = (size_t)BATCH * HDIM * 4;
  const size_t SLOT     = (size_t)BATCH * HDIM * 2;
  const size_t fixed = SZ_BAR + SZ_PROBE + SZ_XBF + SZ_WIH1 + SZ_WLIN + SZ_HPP + SZ_HX + SZ_H1T0 + 2 * SZ_CST;

  int CH = 0;
  const int cands[5] = {64, 32, 16, 8, 4};
  for (int i = 0; i < 5; ++i) {
    int c = cands[i];
    size_t need = fixed + (size_t)(c + 1) * SLOT + (size_t)c * GDIM * BATCH * 2;
    if (need <= ws_size) { CH = c; break; }
  }
  if (CH == 0) {
    float v = 1.0e6f + (float)(ws_size >> 20);
    diag_kernel<<<(32768 + 255) / 256, 256, 0, stream>>>(out, 32768, v);
    return;
  }

  char* ws = (char*)d_ws;
  size_t o = 0;
  unsigned int*   bar   = (unsigned int*)(ws + o);    o += SZ_BAR;
  unsigned int*   probe = (unsigned int*)(ws + o);    o += SZ_PROBE;
  unsigned short* xbf   = (unsigned short*)(ws + o);  o += SZ_XBF;
  unsigned short* wih1b = (unsigned short*)(ws + o);  o += SZ_WIH1;
  unsigned short* wlinb = (unsigned short*)(ws + o);  o += SZ_WLIN;
  unsigned short* h1pp  = (unsigned short*)(ws + o);  o += SZ_HPP;
  unsigned short* hx0   = (unsigned short*)(ws + o);  o += SZ_HX;
  unsigned short* h1t0  = (unsigned short*)(ws + o);  o += SZ_H1T0;
  float*          c0st  = (float*)(ws + o);           o += SZ_CST;
  float*          c1st  = (float*)(ws + o);           o += SZ_CST;
  unsigned short* slab  = (unsigned short*)(ws + o);  o += (size_t)(CH + 1) * SLOT;
  unsigned short* xw1   = (unsigned short*)(ws + o);  o += (size_t)CH * GDIM * BATCH * 2;

  hipMemsetAsync(bar, 0, SZ_BAR, stream);

  conv_bf16<<<(T_STEPS * BATCH * FDIM + 255) / 256, 256, 0, stream>>>(x, xbf, T_STEPS * BATCH * FDIM);
  conv_bf16<<<(GDIM * HDIM + 255) / 256, 256, 0, stream>>>(Wih1, wih1b, GDIM * HDIM);
  conv_bf16<<<(FDIM * HDIM + 255) / 256, 256, 0, stream>>>(Wlin, wlinb, FDIM * HDIM);

  float* hn0 = out + 32768;
  float* hn1 = out + 32768 + 262144;
  float* cn0 = out + 32768 + 524288;
  float* cn1 = out + 32768 + 524288 + 262144;

  unsigned int gen_base = 0;
  for (int ch = 0; ch < T_STEPS / CH; ++ch) {
    int t0 = ch * CH;
    lstm_layer0_kernel<<<256, 1024, 0, stream>>>(
        xbf, Wih0, Whh0, bih0, bhh0, slab, hx0, c0st, t0, CH, gen_base, hn0, cn0, bar, probe);
    gen_base += (unsigned int)CH;   // 1 probe + (CH-1) step stamps
    gemm_bt_xw<<<dim3(CH * 2, 32), 256, 0, stream>>>(
        slab + BATCH * HDIM, wih1b, xw1, HDIM);
    lstm_layer1_kernel<<<256, 1024, 0, stream>>>(
        xw1, Whh1, bih1, bhh1, h1pp, c1st, t0, CH, gen_base, h1t0, hn1, cn1, bar, probe);
    gen_base += (unsigned int)CH;
  }

  y_kernel<<<256, 128, 0, stream>>>(h1t0, wlinb, blin, out);
}

// Round 5
// 3610.272 us; speedup vs baseline: 1.2891x; 1.2891x over previous
//
#include <hip/hip_runtime.h>
#include <stdint.h>

// ---------------------------------------------------------------------------
// 2-layer LSTM (T=256, B=256, F=128, H=1024) for MI355X (gfx950).
// R11: R7 structure (best measured: 3631us) with ONE subsystem changed — the
// group sync. R7 used a counting barrier: 32 same-line fetch_adds (serialized
// RMW ~2-3k cyc) + generation hop + single-spinner release. R10's stamp idea
// was right but botched (all stamps in ONE cache line + per-wave vl1_inv spam
// + reg-staged copies). R11 does it properly:
//   - stamps spread 128B apart (one line per producer WG, no ping-pong)
//   - all-wave parallel poll: lane l polls stamp[l&31], __all() exit -> one
//     vector load per iteration covers all 32 producers
//   - waves go straight from poll to global_load_lds staging (no release
//     barrier); one vl1_inv per wave; 3 syncs/step (was 5)
// Everything else is R7 verbatim: 512 thr / 8 waves, wave=(gate g, K-half kh),
// whh[2][16] in VGPRs, gbuf[8][32][36] f32x4, AS_STRIDE 2080, hoisted x-proj
// in the poll window, hx hot ping-pong (R9), gll width-16 staging.
// Heavy fallback (probe detects non-co-XCD group): release fence on post,
// per-wave agent acquire after poll. Probe salt/poison scheme unchanged.
// ---------------------------------------------------------------------------

typedef __bf16 bf16x8 __attribute__((ext_vector_type(8)));
typedef float  f32x4  __attribute__((ext_vector_type(4)));
typedef unsigned short ushort8v __attribute__((ext_vector_type(8)));
typedef unsigned short ushort4v __attribute__((ext_vector_type(4)));
typedef unsigned short ushort2v __attribute__((ext_vector_type(2)));
typedef unsigned int   uint4v   __attribute__((ext_vector_type(4)));
typedef __attribute__((address_space(1))) unsigned int as1_u32;
typedef __attribute__((address_space(3))) unsigned int as3_u32;

#define T_STEPS 256
#define BATCH   256
#define HDIM    1024
#define GDIM    4096
#define FDIM    128
#define AS_STRIDE 2080   // bytes/row in LDS h slab (R7 measured-good)

static __device__ __forceinline__ float bf2f(unsigned short u) {
  union { unsigned int i; float f; } v; v.i = ((unsigned int)u) << 16; return v.f;
}
static __device__ __forceinline__ unsigned short f2bf(float f) {
  return __builtin_bit_cast(unsigned short, (__bf16)f);
}
static __device__ __forceinline__ float sigm(float x) { return 1.f / (1.f + __expf(-x)); }
static __device__ __forceinline__ float tanh_f(float x) { return 2.f / (1.f + __expf(-2.f * x)) - 1.f; }

static __device__ __forceinline__ void vl1_inv() {
  asm volatile("buffer_inv" ::: "memory");
}

__global__ void conv_bf16(const float* __restrict__ s, unsigned short* __restrict__ d, int n) {
  int i = blockIdx.x * 256 + threadIdx.x;
  if (i < n) d[i] = f2bf(s[i]);
}

__global__ void diag_kernel(float* out, int n, float v) {
  int i = blockIdx.x * 256 + threadIdx.x;
  if (i < n) out[i] = v;
}

// ------------------------- spread-stamp group sync ---------------------------
// stamps = bar + mi*1024 (u32): stamp for producer ni at stamps[ni*32]
// (128B apart -> one cache line each). Monotonic generations; 0xAAAAAAAA
// poison reads negative vs any small target.
__device__ __forceinline__ void post_stamp(unsigned int* st, unsigned int gen, bool fast) {
  if (!fast) __builtin_amdgcn_fence(__ATOMIC_RELEASE, "agent");
  __hip_atomic_store(st, gen, __ATOMIC_RELAXED, __HIP_MEMORY_SCOPE_AGENT);
}

// All waves: lane l polls stamp[l&31]; one vector load per iteration.
__device__ __forceinline__ void poll_all(unsigned int* stamps, unsigned int target) {
  unsigned int* p = stamps + (threadIdx.x & 31) * 32;
  for (unsigned int it = 0; it < (1u << 15); ++it) {
    unsigned int gv = __hip_atomic_load(p, __ATOMIC_RELAXED, __HIP_MEMORY_SCOPE_AGENT);
    if (__all((int)(gv - target) >= 0)) return;
    if (it > 16) __builtin_amdgcn_s_sleep(1);
  }
}

// Stage 32 rows x 1024 cols (64KB) of h into As via global_load_lds width-16.
// 8 rounds x 8 waves x 1KB; LDS dest wave-uniform, lane*16 implicit.
__device__ __forceinline__ void stage64(const unsigned short* __restrict__ hsrc,
                                        char* AsB, int r0, int wv, int lane) {
  #pragma unroll
  for (int p = 0; p < 8; ++p) {
    int idx = p * 8 + wv;                 // 0..63 -> (row, half-row)
    int row = idx >> 1, half = idx & 1;
    const char* gsrc = (const char*)(hsrc + (size_t)(r0 + row) * HDIM + half * 512) + lane * 16;
    char* ldst = AsB + row * AS_STRIDE + half * 1024;
    __builtin_amdgcn_global_load_lds((const as1_u32*)gsrc, (as3_u32*)ldst, 16, 0, 0);
  }
}

// --------------------------- gemm_bt: C = A @ B^T ---------------------------
__global__ __launch_bounds__(256) void gemm_bt_xw(
    const unsigned short* __restrict__ A,
    const unsigned short* __restrict__ B,
    unsigned short* __restrict__ xw,
    int K)
{
  const int tid = threadIdx.x, lane = tid & 63, w = tid >> 6;
  const int m0 = blockIdx.x * 128;
  const int n0 = blockIdx.y * 128;
  __shared__ unsigned short As[128 * 64];
  __shared__ unsigned short Bs[128 * 64];
  const int mrow0 = (w & 1) * 64, ncol0 = (w >> 1) * 64;
  const int quad = lane >> 4;

  f32x4 acc[4][4];
  #pragma unroll
  for (int i = 0; i < 4; ++i)
    #pragma unroll
    for (int j = 0; j < 4; ++j) acc[i][j] = f32x4{0.f, 0.f, 0.f, 0.f};

  const int kiter = K >> 6;
  for (int ki = 0; ki < kiter; ++ki) {
    const int k0 = ki * 64;
    __syncthreads();
    #pragma unroll
    for (int i = 0; i < 4; ++i) {
      int obase = (w * 4 + i) * 1024;          // wave-uniform LDS byte base
      int o = obase + lane * 16;
      int row = o >> 7; int kb = o & 127;
      const char* ga = (const char*)A + ((size_t)(m0 + row) * K + k0) * 2 + kb;
      const char* gb = (const char*)B + ((size_t)(n0 + row) * K + k0) * 2 + kb;
      __builtin_amdgcn_global_load_lds((const as1_u32*)ga, (as3_u32*)((char*)As + obase), 16, 0, 0);
      __builtin_amdgcn_global_load_lds((const as1_u32*)gb, (as3_u32*)((char*)Bs + obase), 16, 0, 0);
    }
    __syncthreads();
    #pragma unroll
    for (int kk = 0; kk < 2; ++kk) {
      bf16x8 af[4], bfr[4];
      #pragma unroll
      for (int mt = 0; mt < 4; ++mt)
        af[mt] = *(const bf16x8*)(As + (mrow0 + mt * 16 + (lane & 15)) * 64 + kk * 32 + quad * 8);
      #pragma unroll
      for (int nt = 0; nt < 4; ++nt)
        bfr[nt] = *(const bf16x8*)(Bs + (ncol0 + nt * 16 + (lane & 15)) * 64 + kk * 32 + quad * 8);
      #pragma unroll
      for (int mt = 0; mt < 4; ++mt)
        #pragma unroll
        for (int nt = 0; nt < 4; ++nt)
          acc[mt][nt] = __builtin_amdgcn_mfma_f32_16x16x32_bf16(af[mt], bfr[nt], acc[mt][nt], 0, 0, 0);
    }
  }
  #pragma unroll
  for (int mt = 0; mt < 4; ++mt) {
    int m = m0 + mrow0 + mt * 16 + quad * 4;
    int tl = m >> 8, b = m & 255;
    #pragma unroll
    for (int nt = 0; nt < 4; ++nt) {
      int col = n0 + ncol0 + nt * 16 + (lane & 15);
      ushort4v v;
      v.x = f2bf(acc[mt][nt][0]); v.y = f2bf(acc[mt][nt][1]);
      v.z = f2bf(acc[mt][nt][2]); v.w = f2bf(acc[mt][nt][3]);
      *(ushort4v*)(xw + ((size_t)tl * GDIM + col) * BATCH + b) = v;
    }
  }
}

// ---------------- probe: validate intra-XCD visibility for this group --------
// token plain-store -> drain -> stamp post -> all-wave parallel poll ->
// vL1 inv -> tid0 reads all 32 tokens. d_ws re-poisoned 0xAA pre-launch, so
// a cross-XCD member always mismatches -> heavy fences all launch.
__device__ __forceinline__ bool probe_chk(unsigned int* probeBuf, unsigned int* stamps,
                                          unsigned int salt, unsigned int target,
                                          unsigned int* flagLds) {
  const int wg = blockIdx.x, mi = wg & 7, ni = wg >> 3;
  const int tid = threadIdx.x;
  if (tid == 0) probeBuf[wg * 32] = salt ^ (unsigned int)wg;
  __syncthreads();   // drains token store to L2
  if (tid == 0)
    __hip_atomic_store(stamps + ni * 32, target, __ATOMIC_RELAXED, __HIP_MEMORY_SCOPE_AGENT);
  poll_all(stamps, target);
  vl1_inv();
  if (tid == 0) {
    unsigned int bad = 0;
    for (int k = 0; k < 32; ++k) {
      int member = mi + 8 * k;
      unsigned int v = probeBuf[member * 32];
      if (v != (salt ^ (unsigned int)member)) bad = 1;
    }
    *flagLds = bad;
  }
  __syncthreads();
  return (*flagLds == 0);
}

// --------------------------- layer 0: fused persistent chunk -----------------
// 256 WGs x 512 thr, 1/CU. WG (mi=wg&7, ni=wg>>3): rows [32mi,+32), cols [32ni,+32).
// Wave wv: gate g=wv&3, K-half kh=wv>>2. whh[2][16]=128 VGPR/wave, 2 waves/SIMD.
__global__ __launch_bounds__(512, 2) void lstm_layer0_kernel(
    const unsigned short* __restrict__ xbf,  // (T,B,F) bf16
    const float* __restrict__ Wih,           // (4096,128) fp32
    const float* __restrict__ Whh,           // (4096,1024) fp32
    const float* __restrict__ bih,
    const float* __restrict__ bhh,
    unsigned short* __restrict__ slab,       // (ch_len+1, B, H) bf16, gemm feed
    unsigned short* __restrict__ hx,         // 2-slot ping-pong exchange (hot)
    float* __restrict__ cstate,              // (B,H) fp32
    int t0, int ch_len, unsigned int gen_base,
    float* __restrict__ dout_h,
    float* __restrict__ dout_c,
    unsigned int* __restrict__ bar,
    unsigned int* __restrict__ probe)
{
  const int tid = threadIdx.x, lane = tid & 63, wv = tid >> 6;   // wv 0..7
  const int quad = lane >> 4, l15 = lane & 15;
  const int g = wv & 3, kh = wv >> 2;
  const int wg = blockIdx.x;
  const int mi = wg & 7, ni = wg >> 3;
  const int r0 = mi * 32, hc0 = ni * 32;
  unsigned int* stamps = bar + mi * 1024;   // 32 stamps, 128B apart

  __shared__ unsigned short As[32 * (AS_STRIDE / 2)];
  __shared__ float gbuf[8][32][36];
  __shared__ unsigned int flagLds;

  // W_hh fragment: gate g, K-half kh (32 cols x 512 k, bf16 in regs)
  bf16x8 whh[2][16];
  #pragma unroll
  for (int nt = 0; nt < 2; ++nt) {
    const float* wrow = Whh + (size_t)(g * HDIM + hc0 + nt * 16 + l15) * HDIM + kh * 512 + quad * 8;
    #pragma unroll
    for (int kk = 0; kk < 16; ++kk) {
      f32x4 f0 = *(const f32x4*)(wrow + kk * 32);
      f32x4 f1 = *(const f32x4*)(wrow + kk * 32 + 4);
      bf16x8 r;
      r[0] = (__bf16)f0[0]; r[1] = (__bf16)f0[1]; r[2] = (__bf16)f0[2]; r[3] = (__bf16)f0[3];
      r[4] = (__bf16)f1[0]; r[5] = (__bf16)f1[1]; r[6] = (__bf16)f1[2]; r[7] = (__bf16)f1[3];
      whh[nt][kk] = r;
    }
  }
  // W_ih fragment: K=128 split across kh (64 each)
  bf16x8 wih[2][2];
  #pragma unroll
  for (int nt = 0; nt < 2; ++nt) {
    const float* wrow = Wih + (size_t)(g * HDIM + hc0 + nt * 16 + l15) * FDIM + kh * 64 + quad * 8;
    #pragma unroll
    for (int kk = 0; kk < 2; ++kk) {
      f32x4 f0 = *(const f32x4*)(wrow + kk * 32);
      f32x4 f1 = *(const f32x4*)(wrow + kk * 32 + 4);
      bf16x8 r;
      r[0] = (__bf16)f0[0]; r[1] = (__bf16)f0[1]; r[2] = (__bf16)f0[2]; r[3] = (__bf16)f0[3];
      r[4] = (__bf16)f1[0]; r[5] = (__bf16)f1[1]; r[6] = (__bf16)f1[2]; r[7] = (__bf16)f1[3];
      wih[nt][kk] = r;
    }
  }

  const int hcl = tid & 31, rg2 = tid >> 5;   // rg2 in [0,16): rows rg2*2+{0,1}
  float bias[4];
  #pragma unroll
  for (int b4 = 0; b4 < 4; ++b4)
    bias[b4] = bih[b4 * HDIM + hc0 + hcl] + bhh[b4 * HDIM + hc0 + hcl];

  float c[2];
  #pragma unroll
  for (int r = 0; r < 2; ++r)
    c[r] = (t0 == 0) ? 0.f : cstate[(size_t)(r0 + rg2 * 2 + r) * HDIM + hc0 + hcl];

  unsigned int salt = 0x9E3779B9u ^ (gen_base * 2654435761u);
  bool fast = probe_chk(probe, stamps, salt, gen_base + 1u, &flagLds);

  const int tend = t0 + ch_len;

  // prologue: cross-kernel h stage (prev dispatch's stores, stream-visible)
  if (t0 > 0)
    stage64(hx + (size_t)((t0 - 1) & 1) * (BATCH * HDIM), (char*)As, r0, wv, lane);

  // prologue: x-projection for the first step
  f32x4 acc[2][2];
  #pragma unroll
  for (int mt = 0; mt < 2; ++mt)
    #pragma unroll
    for (int nt = 0; nt < 2; ++nt) acc[mt][nt] = f32x4{0.f, 0.f, 0.f, 0.f};
  #pragma unroll
  for (int j = 0; j < 2; ++j) {
    bf16x8 af[2];
    #pragma unroll
    for (int mt = 0; mt < 2; ++mt)
      af[mt] = *(const bf16x8*)(xbf + (size_t)(t0 * BATCH + r0 + mt * 16 + l15) * FDIM + kh * 64 + j * 32 + quad * 8);
    #pragma unroll
    for (int mt = 0; mt < 2; ++mt)
      #pragma unroll
      for (int nt = 0; nt < 2; ++nt)
        acc[mt][nt] = __builtin_amdgcn_mfma_f32_16x16x32_bf16(af[mt], wih[nt][j], acc[mt][nt], 0, 0, 0);
  }
  __syncthreads();   // prologue stage visible (vmcnt drained by barrier)

  #pragma unroll 1
  for (int t = t0; t < tend; ++t) {
    if (t > 0) {
      #pragma unroll
      for (int j = 0; j < 16; ++j) {
        bf16x8 af[2];
        #pragma unroll
        for (int mt = 0; mt < 2; ++mt)
          af[mt] = *(const bf16x8*)((const char*)As + (mt * 16 + l15) * AS_STRIDE + (kh * 16 + j) * 64 + quad * 16);
        #pragma unroll
        for (int mt = 0; mt < 2; ++mt)
          #pragma unroll
          for (int nt = 0; nt < 2; ++nt)
            acc[mt][nt] = __builtin_amdgcn_mfma_f32_16x16x32_bf16(af[mt], whh[nt][j], acc[mt][nt], 0, 0, 0);
      }
    }

    // gbuf write — per-wave-exclusive slot; readers gated by sync A; As reads
    // all complete before any wave passes sync A (barrier waits lgkmcnt).
    #pragma unroll
    for (int mt = 0; mt < 2; ++mt)
      #pragma unroll
      for (int nt = 0; nt < 2; ++nt) {
        int hl = nt * 16 + l15;
        int rq = mt * 16 + quad * 4;
        *(f32x4*)&gbuf[wv][hl][rq] = acc[mt][nt];
      }
    __syncthreads();   // (A) gbuf visible

    unsigned short* hdst = slab + (size_t)(t - t0 + 1) * (BATCH * HDIM);
    unsigned short* hxd  = hx + (size_t)(t & 1) * (BATCH * HDIM);
    #pragma unroll
    for (int r = 0; r < 2; ++r) {
      int row = rg2 * 2 + r;
      float gi = gbuf[0][hcl][row] + gbuf[4][hcl][row] + bias[0];
      float gf = gbuf[1][hcl][row] + gbuf[5][hcl][row] + bias[1];
      float gg = gbuf[2][hcl][row] + gbuf[6][hcl][row] + bias[2];
      float go = gbuf[3][hcl][row] + gbuf[7][hcl][row] + bias[3];
      float iv = sigm(gi), fv = sigm(gf), gv = tanh_f(gg), ov = sigm(go);
      float cn = fv * c[r] + iv * gv;
      c[r] = cn;
      float hv = ov * tanh_f(cn);
      int gidx = (r0 + row) * HDIM + hc0 + hcl;
      unsigned short hb = f2bf(hv);
      hxd[gidx] = hb;        // hot exchange
      hdst[gidx] = hb;       // gemm feed
      if (t == tend - 1) cstate[gidx] = cn;
      if (t == T_STEPS - 1) { dout_h[gidx] = hv; dout_c[gidx] = cn; }
    }
    __syncthreads();   // (B) drains h stores (vmcnt 0) -> visible at L2

    if (t != tend - 1) {
      const unsigned int tgt = gen_base + 2u + (unsigned int)(t - t0);
      if (tid == 0) post_stamp(stamps + ni * 32, tgt, fast);

      // hoisted: x-projection for step t+1 (independent of h(t)) fills the
      // poll window.
      #pragma unroll
      for (int mt = 0; mt < 2; ++mt)
        #pragma unroll
        for (int nt = 0; nt < 2; ++nt) acc[mt][nt] = f32x4{0.f, 0.f, 0.f, 0.f};
      #pragma unroll
      for (int j = 0; j < 2; ++j) {
        bf16x8 af[2];
        #pragma unroll
        for (int mt = 0; mt < 2; ++mt)
          af[mt] = *(const bf16x8*)(xbf + (size_t)((t + 1) * BATCH + r0 + mt * 16 + l15) * FDIM + kh * 64 + j * 32 + quad * 8);
        #pragma unroll
        for (int mt = 0; mt < 2; ++mt)
          #pragma unroll
          for (int nt = 0; nt < 2; ++nt)
            acc[mt][nt] = __builtin_amdgcn_mfma_f32_16x16x32_bf16(af[mt], wih[nt][j], acc[mt][nt], 0, 0, 0);
      }

      poll_all(stamps, tgt);
      if (fast) vl1_inv();
      else __builtin_amdgcn_fence(__ATOMIC_ACQUIRE, "agent");
      stage64(hx + (size_t)(t & 1) * (BATCH * HDIM), (char*)As, r0, wv, lane);
      __syncthreads();   // (C) all chunks staged (vmcnt drained by barrier)
    }
  }
}

// --------------------------- layer 1: persistent chunk ----------------------
__global__ __launch_bounds__(512, 2) void lstm_layer1_kernel(
    const unsigned short* __restrict__ xw,   // (ch_len, 4096, 256) bf16
    const float* __restrict__ Whh,
    const float* __restrict__ bih,
    const float* __restrict__ bhh,
    unsigned short* __restrict__ hpp,        // 2-slot ping-pong
    float* __restrict__ cstate,
    int t0, int ch_len, unsigned int gen_base,
    unsigned short* __restrict__ h1t0,
    float* __restrict__ dout_h,
    float* __restrict__ dout_c,
    unsigned int* __restrict__ bar,
    unsigned int* __restrict__ probe)
{
  const int tid = threadIdx.x, lane = tid & 63, wv = tid >> 6;
  const int quad = lane >> 4, l15 = lane & 15;
  const int g = wv & 3, kh = wv >> 2;
  const int wg = blockIdx.x;
  const int mi = wg & 7, ni = wg >> 3;
  const int r0 = mi * 32, hc0 = ni * 32;
  unsigned int* stamps = bar + mi * 1024;

  __shared__ unsigned short As[32 * (AS_STRIDE / 2)];
  __shared__ float gbuf[8][32][36];
  __shared__ unsigned int flagLds;

  bf16x8 whh[2][16];
  #pragma unroll
  for (int nt = 0; nt < 2; ++nt) {
    const float* wrow = Whh + (size_t)(g * HDIM + hc0 + nt * 16 + l15) * HDIM + kh * 512 + quad * 8;
    #pragma unroll
    for (int kk = 0; kk < 16; ++kk) {
      f32x4 f0 = *(const f32x4*)(wrow + kk * 32);
      f32x4 f1 = *(const f32x4*)(wrow + kk * 32 + 4);
      bf16x8 r;
      r[0] = (__bf16)f0[0]; r[1] = (__bf16)f0[1]; r[2] = (__bf16)f0[2]; r[3] = (__bf16)f0[3];
      r[4] = (__bf16)f1[0]; r[5] = (__bf16)f1[1]; r[6] = (__bf16)f1[2]; r[7] = (__bf16)f1[3];
      whh[nt][kk] = r;
    }
  }

  const int hcl = tid & 31, rg2 = tid >> 5;
  float bias[4];
  #pragma unroll
  for (int b4 = 0; b4 < 4; ++b4)
    bias[b4] = bih[b4 * HDIM + hc0 + hcl] + bhh[b4 * HDIM + hc0 + hcl];

  float c[2];
  #pragma unroll
  for (int r = 0; r < 2; ++r)
    c[r] = (t0 == 0) ? 0.f : cstate[(size_t)(r0 + rg2 * 2 + r) * HDIM + hc0 + hcl];

  unsigned int salt = 0xB5297A4Du ^ (gen_base * 2654435761u);
  bool fast = probe_chk(probe, stamps, salt, gen_base + 1u, &flagLds);

  const int tend = t0 + ch_len;

  // prologue: cross-kernel h stage + xw loads for first step
  if (t0 > 0)
    stage64(hpp + (size_t)((t0 - 1) & 1) * (BATCH * HDIM), (char*)As, r0, wv, lane);
  float xwv[4][2];
  #pragma unroll
  for (int g4 = 0; g4 < 4; ++g4) {
    const unsigned short* xp =
        xw + ((size_t)0 * GDIM + g4 * HDIM + hc0 + hcl) * BATCH + r0 + rg2 * 2;
    ushort2v u = *(const ushort2v*)xp;
    xwv[g4][0] = bf2f(u.x); xwv[g4][1] = bf2f(u.y);
  }
  __syncthreads();

  #pragma unroll 1
  for (int t = t0; t < tend; ++t) {
    f32x4 acc[2][2];
    #pragma unroll
    for (int mt = 0; mt < 2; ++mt)
      #pragma unroll
      for (int nt = 0; nt < 2; ++nt) acc[mt][nt] = f32x4{0.f, 0.f, 0.f, 0.f};

    if (t > 0) {
      #pragma unroll
      for (int j = 0; j < 16; ++j) {
        bf16x8 af[2];
        #pragma unroll
        for (int mt = 0; mt < 2; ++mt)
          af[mt] = *(const bf16x8*)((const char*)As + (mt * 16 + l15) * AS_STRIDE + (kh * 16 + j) * 64 + quad * 16);
        #pragma unroll
        for (int mt = 0; mt < 2; ++mt)
          #pragma unroll
          for (int nt = 0; nt < 2; ++nt)
            acc[mt][nt] = __builtin_amdgcn_mfma_f32_16x16x32_bf16(af[mt], whh[nt][j], acc[mt][nt], 0, 0, 0);
      }
    }

    #pragma unroll
    for (int mt = 0; mt < 2; ++mt)
      #pragma unroll
      for (int nt = 0; nt < 2; ++nt) {
        int hl = nt * 16 + l15;
        int rq = mt * 16 + quad * 4;
        *(f32x4*)&gbuf[wv][hl][rq] = acc[mt][nt];
      }
    __syncthreads();   // (A)

    unsigned short* hdst = hpp + (size_t)(t & 1) * (BATCH * HDIM);
    #pragma unroll
    for (int r = 0; r < 2; ++r) {
      int row = rg2 * 2 + r;
      float gi = gbuf[0][hcl][row] + gbuf[4][hcl][row] + xwv[0][r] + bias[0];
      float gf = gbuf[1][hcl][row] + gbuf[5][hcl][row] + xwv[1][r] + bias[1];
      float gg = gbuf[2][hcl][row] + gbuf[6][hcl][row] + xwv[2][r] + bias[2];
      float go = gbuf[3][hcl][row] + gbuf[7][hcl][row] + xwv[3][r] + bias[3];
      float iv = sigm(gi), fv = sigm(gf), gv = tanh_f(gg), ov = sigm(go);
      float cn = fv * c[r] + iv * gv;
      c[r] = cn;
      float hv = ov * tanh_f(cn);
      int gidx = (r0 + row) * HDIM + hc0 + hcl;
      hdst[gidx] = f2bf(hv);
      if (h1t0 != nullptr && t == 0) h1t0[gidx] = f2bf(hv);
      if (t == tend - 1) cstate[gidx] = cn;
      if (t == T_STEPS - 1) { dout_h[gidx] = hv; dout_c[gidx] = cn; }
    }
    __syncthreads();   // (B)

    if (t != tend - 1) {
      const unsigned int tgt = gen_base + 2u + (unsigned int)(t - t0);
      if (tid == 0) post_stamp(stamps + ni * 32, tgt, fast);

      // hoisted: xw loads for step t+1 fill the poll window
      #pragma unroll
      for (int g4 = 0; g4 < 4; ++g4) {
        const unsigned short* xp =
            xw + ((size_t)(t + 1 - t0) * GDIM + g4 * HDIM + hc0 + hcl) * BATCH + r0 + rg2 * 2;
        ushort2v u = *(const ushort2v*)xp;
        xwv[g4][0] = bf2f(u.x); xwv[g4][1] = bf2f(u.y);
      }

      poll_all(stamps, tgt);
      if (fast) vl1_inv();
      else __builtin_amdgcn_fence(__ATOMIC_ACQUIRE, "agent");
      stage64(hpp + (size_t)(t & 1) * (BATCH * HDIM), (char*)As, r0, wv, lane);
      __syncthreads();   // (C)
    }
  }
}

__global__ void y_kernel(const unsigned short* __restrict__ h1t0,
                         const unsigned short* __restrict__ wlin,
                         const float* __restrict__ blin,
                         float* __restrict__ y)
{
  int b = blockIdx.x;
  int f = threadIdx.x;
  const ushort8v* hp = (const ushort8v*)(h1t0 + (size_t)b * HDIM);
  const ushort8v* wp = (const ushort8v*)(wlin + (size_t)f * HDIM);
  float acc = 0.f;
  for (int i = 0; i < HDIM / 8; ++i) {
    ushort8v hv = hp[i], wvv = wp[i];
    #pragma unroll
    for (int j = 0; j < 8; ++j) acc += bf2f(hv[j]) * bf2f(wvv[j]);
  }
  y[b * FDIM + f] = acc + blin[f];
}

// ---------------------------------------------------------------------------
extern "C" void kernel_launch(void* const* d_in, const int* in_sizes, int n_in,
                              void* d_out, int out_size, void* d_ws, size_t ws_size,
                              hipStream_t stream) {
  (void)in_sizes; (void)n_in; (void)out_size;
  const float* x    = (const float*)d_in[0];
  const float* Wih0 = (const float*)d_in[1];
  const float* Whh0 = (const float*)d_in[2];
  const float* bih0 = (const float*)d_in[3];
  const float* bhh0 = (const float*)d_in[4];
  const float* Wih1 = (const float*)d_in[5];
  const float* Whh1 = (const float*)d_in[6];
  const float* bih1 = (const float*)d_in[7];
  const float* bhh1 = (const float*)d_in[8];
  const float* Wlin = (const float*)d_in[9];
  const float* blin = (const float*)d_in[10];
  float* out = (float*)d_out;

  const size_t SZ_BAR   = 32768;   // 8 groups x 32 stamps x 128B
  const size_t SZ_PROBE = 32768;
  const size_t SZ_XBF   = (size_t)T_STEPS * BATCH * FDIM * 2;
  const size_t SZ_WIH1  = (size_t)GDIM * HDIM * 2;
  const size_t SZ_WLIN  = (size_t)FDIM * HDIM * 2;
  const size_t SZ_HPP   = (size_t)2 * BATCH * HDIM * 2;
  const size_t SZ_HX    = (size_t)2 * BATCH * HDIM * 2;
  const size_t SZ_H1T0  = (size_t)BATCH * HDIM * 2;
  const size_t SZ_CST   = (size_t)BATCH * HDIM * 4;
  const size_t SLOT     = (size_t)BATCH * HDIM * 2;
  const size_t fixed = SZ_BAR + SZ_PROBE + SZ_XBF + SZ_WIH1 + SZ_WLIN + SZ_HPP + SZ_HX + SZ_H1T0 + 2 * SZ_CST;

  int CH = 0;
  const int cands[5] = {64, 32, 16, 8, 4};
  for (int i = 0; i < 5; ++i) {
    int c = cands[i];
    size_t need = fixed + (size_t)(c + 1) * SLOT + (size_t)c * GDIM * BATCH * 2;
    if (need <= ws_size) { CH = c; break; }
  }
  if (CH == 0) {
    float v = 1.0e6f + (float)(ws_size >> 20);
    diag_kernel<<<(32768 + 255) / 256, 256, 0, stream>>>(out, 32768, v);
    return;
  }

  char* ws = (char*)d_ws;
  size_t o = 0;
  unsigned int*   bar   = (unsigned int*)(ws + o);    o += SZ_BAR;
  unsigned int*   probe = (unsigned int*)(ws + o);    o += SZ_PROBE;
  unsigned short* xbf   = (unsigned short*)(ws + o);  o += SZ_XBF;
  unsigned short* wih1b = (unsigned short*)(ws + o);  o += SZ_WIH1;
  unsigned short* wlinb = (unsigned short*)(ws + o);  o += SZ_WLIN;
  unsigned short* h1pp  = (unsigned short*)(ws + o);  o += SZ_HPP;
  unsigned short* hx0   = (unsigned short*)(ws + o);  o += SZ_HX;
  unsigned short* h1t0  = (unsigned short*)(ws + o);  o += SZ_H1T0;
  float*          c0st  = (float*)(ws + o);           o += SZ_CST;
  float*          c1st  = (float*)(ws + o);           o += SZ_CST;
  unsigned short* slab  = (unsigned short*)(ws + o);  o += (size_t)(CH + 1) * SLOT;
  unsigned short* xw1   = (unsigned short*)(ws + o);  o += (size_t)CH * GDIM * BATCH * 2;

  hipMemsetAsync(bar, 0, SZ_BAR, stream);

  conv_bf16<<<(T_STEPS * BATCH * FDIM + 255) / 256, 256, 0, stream>>>(x, xbf, T_STEPS * BATCH * FDIM);
  conv_bf16<<<(GDIM * HDIM + 255) / 256, 256, 0, stream>>>(Wih1, wih1b, GDIM * HDIM);
  conv_bf16<<<(FDIM * HDIM + 255) / 256, 256, 0, stream>>>(Wlin, wlinb, FDIM * HDIM);

  float* hn0 = out + 32768;
  float* hn1 = out + 32768 + 262144;
  float* cn0 = out + 32768 + 524288;
  float* cn1 = out + 32768 + 524288 + 262144;

  unsigned int gen_base = 0;
  for (int ch = 0; ch < T_STEPS / CH; ++ch) {
    int t0 = ch * CH;
    lstm_layer0_kernel<<<256, 512, 0, stream>>>(
        xbf, Wih0, Whh0, bih0, bhh0, slab, hx0, c0st, t0, CH, gen_base, hn0, cn0, bar, probe);
    gen_base += (unsigned int)CH;   // 1 probe + (CH-1) step stamps
    gemm_bt_xw<<<dim3(CH * 2, 32), 256, 0, stream>>>(
        slab + BATCH * HDIM, wih1b, xw1, HDIM);
    lstm_layer1_kernel<<<256, 512, 0, stream>>>(
        xw1, Whh1, bih1, bhh1, h1pp, c1st, t0, CH, gen_base, h1t0, hn1, cn1, bar, probe);
    gen_base += (unsigned int)CH;
  }

  y_kernel<<<256, 128, 0, stream>>>(h1t0, wlinb, blin, out);
}